// Round 1
// baseline (67.288 us; speedup 1.0000x reference)
//
#include <hip/hip_runtime.h>

// Problem shape (fixed by reference setup_inputs):
//   bert_emb:    [B=4, Lp=256, D=768] fp32
//   pieces2word: [B=4, Lw=200, Lp=256] int32 (0/1)
//   out:         [B=4, Lw=200, D=768] fp32
// out[b,w,d] = max over {p : mask[b,w,p]!=0} of emb[b,p,d], else global min(emb).
//
// R11 — uniform-branch piece skip (change vs R6 is ONLY the inner merge):
//  The per-word 32-bit masks m[j] are wave-uniform (ballot -> SGPR). Instead
//  of branchless cndmask+max (4 VALU per (piece,word) float2, 640 VALU/wave),
//  test each bit on the SCALAR pipe and branch:
//    - bit==0 (p=0.5): skip, 0 VALU
//    - bit==1:         fmax(acc, v) directly, no cndmask (2 VALU)
//  -> ~160 VALU (avg) + 320 SALU per wave main loop. SALU issues on the
//  scalar pipe in parallel with other waves' VALU; branch-redirect bubbles
//  hidden by 7.5 waves/SIMD occupancy.
//  The empty `asm volatile` in the if-body blocks LLVM if-conversion (a
//  volatile asm cannot be speculated), forcing a real s_cbranch on the
//  uniform condition instead of v_cndmask re-materialization.
//
// Everything else identical to R6 (best previous: 67.3 us total, kernel
// ~10.5 us): 960 blocks x 512 threads, 8-way piece split, LDS merge.

#define B_  4
#define LP_ 256
#define LW_ 200
#define D_  768
#define D2_ (D_ / 2)              // 384 float2 per row
#define CHUNKS 6                  // 6 chunks x 128 floats (1 float2 per lane)
#define W_  5                     // words per block
#define WG_ (LW_ / W_)            // 40 word-groups
#define NBLK (B_ * CHUNKS * WG_)  // 960 blocks
#define SEGS 8                    // waves (piece segments) per block
#define PPS 32                    // pieces per segment

__global__ __launch_bounds__(512) void word_max_scan(
    const float* __restrict__ emb, const int* __restrict__ p2w,
    float* __restrict__ out)
{
    const int blk   = blockIdx.x;
    const int wg    = blk % WG_;
    const int rest  = blk / WG_;
    const int chunk = rest % CHUNKS;
    const int b     = rest / CHUNKS;
    const int lane  = threadIdx.x & 63;
    const int s     = threadIdx.x >> 6;     // piece segment 0..7
    const int w0    = wg * W_;

    // Each wave ballots a 32-bit mask for its 32 pieces, per word.
    unsigned int m[W_];
    const int pc = s * PPS + (lane & 31);
    #pragma unroll
    for (int j = 0; j < W_; ++j) {
        const int* mrow = p2w + (b * LW_ + w0 + j) * LP_;
        m[j] = (unsigned int)__ballot((lane < 32) && (mrow[pc] != 0));
    }

    const float ninf = __uint_as_float(0xFF800000u);
    float2 acc[W_];
    #pragma unroll
    for (int j = 0; j < W_; ++j) acc[j] = make_float2(ninf, ninf);

    // Wave's row stream: rows [32s, 32s+32), column = chunk*64 + lane (float2).
    const float2* rps = (const float2*)(emb + (size_t)b * LP_ * D_)
                        + chunk * 64 + lane + (size_t)(s * PPS) * D2_;

    #pragma unroll
    for (int g = 0; g < PPS; g += 8) {
        float2 v[8];
        #pragma unroll
        for (int k = 0; k < 8; ++k)
            v[k] = rps[(size_t)(g + k) * D2_];
        #pragma unroll
        for (int k = 0; k < 8; ++k) {
            #pragma unroll
            for (int j = 0; j < W_; ++j) {
                // m[j] is wave-uniform -> scalar bit test + s_cbranch.
                if ((m[j] >> (g + k)) & 1u) {
                    acc[j].x = fmaxf(acc[j].x, v[k].x);
                    acc[j].y = fmaxf(acc[j].y, v[k].y);
                    // Non-speculatable: forbids if-conversion back to
                    // cndmask; emits a real uniform branch. Zero insts.
                    asm volatile("" : "+v"(acc[j].x), "+v"(acc[j].y));
                }
            }
        }
    }

    // Merge the 8 segments via LDS.
    __shared__ float2 sacc[SEGS][W_][64];
    __shared__ unsigned int smask[SEGS][W_];
    #pragma unroll
    for (int j = 0; j < W_; ++j) sacc[s][j][lane] = acc[j];
    if (lane == 0) {
        #pragma unroll
        for (int j = 0; j < W_; ++j) smask[s][j] = m[j];
    }
    __syncthreads();

    // Wave j (< W_) finalizes word j.
    if (s < W_) {
        const int j = s;
        float2 r = sacc[0][j][lane];
        #pragma unroll
        for (int seg = 1; seg < SEGS; ++seg) {
            r.x = fmaxf(r.x, sacc[seg][j][lane].x);
            r.y = fmaxf(r.y, sacc[seg][j][lane].y);
        }
        unsigned int om = 0;
        #pragma unroll
        for (int seg = 0; seg < SEGS; ++seg) om |= smask[seg][j];

        if (om == 0u) {
            // Never taken for the fixed inputs; correct fallback = global
            // min over ALL of emb (reference min_value semantics).
            const float4* x = (const float4*)emb;
            const int n4 = (B_ * LP_ * D_) / 4;
            float mn = __uint_as_float(0x7F800000u);  // +inf
            for (int i = lane; i < n4; i += 64) {
                float4 vv = x[i];
                mn = fminf(mn, fminf(fminf(vv.x, vv.y), fminf(vv.z, vv.w)));
            }
            #pragma unroll
            for (int off = 32; off > 0; off >>= 1)
                mn = fminf(mn, __shfl_down(mn, off, 64));
            mn = __shfl(mn, 0, 64);
            r = make_float2(mn, mn);
        }

        float2* op = (float2*)out + (size_t)(b * LW_ + w0 + j) * D2_
                     + chunk * 64 + lane;
        *op = r;
    }
}

extern "C" void kernel_launch(void* const* d_in, const int* in_sizes, int n_in,
                              void* d_out, int out_size, void* d_ws, size_t ws_size,
                              hipStream_t stream) {
    const float* emb = (const float*)d_in[0];
    const int*   p2w = (const int*)d_in[1];
    float*       out = (float*)d_out;
    (void)d_ws; (void)ws_size;

    word_max_scan<<<NBLK, 512, 0, stream>>>(emb, p2w, out);
}

// Round 2
// 66.643 us; speedup vs baseline: 1.0097x; 1.0097x over previous
//
#include <hip/hip_runtime.h>

// Problem shape (fixed by reference setup_inputs):
//   bert_emb:    [B=4, Lp=256, D=768] fp32
//   pieces2word: [B=4, Lw=200, Lp=256] int32 (0/1)
//   out:         [B=4, Lw=200, D=768] fp32
// out[b,w,d] = max over {p : mask[b,w,p]!=0} of emb[b,p,d], else global min(emb).
//
// R12 — isolated v_max3_f32 pair-merge (R9 retried WITHOUT the XCD swizzle;
// R11's uniform-branch reverted — it was neutral: branch-redirect bubbles ate
// the VALU savings).
//  Merge cost per 2 pieces per float: 2 v_cndmask + 1 v_max3  (1.5 VALU/elem)
//  vs R6's 2 v_cndmask + 2 v_max      (2.0 VALU/elem).
//  -> main-loop VALU 640 -> 480 insts/wave, ~25% off the VALU-issue floor.
//  v_max3 forced by inline asm (guaranteed emission; pure, non-volatile so
//  the scheduler can still move it). Bit-exact: no NaNs in inputs, -inf is
//  the identity; selection semantics identical to R6.
//
// Everything else identical to R6 (best: 67.26 us total, kernel ~10.5 us):
//  - 960 blocks x 512 threads (8 waves): block = (b, chunk of 128 floats,
//    group of W=5 words). Wave s owns pieces [32s, 32s+32): ballots its own
//    5x32-bit word-masks, streams its 32 emb row-chunks once (unroll-8
//    dwordx2 loads), merges into 5 float2 accumulators. 30 waves/CU.
//  - End: LDS merge of 8 segments (20.5 KB), float2 stores.
//  - acc init = -inf is bit-exact; empty-mask word (never for fixed inputs)
//    -> correct global-min fallback.

#define B_  4
#define LP_ 256
#define LW_ 200
#define D_  768
#define D2_ (D_ / 2)              // 384 float2 per row
#define CHUNKS 6                  // 6 chunks x 128 floats (1 float2 per lane)
#define W_  5                     // words per block
#define WG_ (LW_ / W_)            // 40 word-groups
#define NBLK (B_ * CHUNKS * WG_)  // 960 blocks
#define SEGS 8                    // waves (piece segments) per block
#define PPS 32                    // pieces per segment

__global__ __launch_bounds__(512) void word_max_scan(
    const float* __restrict__ emb, const int* __restrict__ p2w,
    float* __restrict__ out)
{
    const int blk   = blockIdx.x;
    const int wg    = blk % WG_;
    const int rest  = blk / WG_;
    const int chunk = rest % CHUNKS;
    const int b     = rest / CHUNKS;
    const int lane  = threadIdx.x & 63;
    const int s     = threadIdx.x >> 6;     // piece segment 0..7
    const int w0    = wg * W_;

    // Each wave ballots a 32-bit mask for its 32 pieces, per word.
    unsigned int m[W_];
    const int pc = s * PPS + (lane & 31);
    #pragma unroll
    for (int j = 0; j < W_; ++j) {
        const int* mrow = p2w + (b * LW_ + w0 + j) * LP_;
        m[j] = (unsigned int)__ballot((lane < 32) && (mrow[pc] != 0));
    }

    const float ninf = __uint_as_float(0xFF800000u);
    float2 acc[W_];
    #pragma unroll
    for (int j = 0; j < W_; ++j) acc[j] = make_float2(ninf, ninf);

    // Wave's row stream: rows [32s, 32s+32), column = chunk*64 + lane (float2).
    const float2* rps = (const float2*)(emb + (size_t)b * LP_ * D_)
                        + chunk * 64 + lane + (size_t)(s * PPS) * D2_;

    #pragma unroll
    for (int g = 0; g < PPS; g += 8) {
        float2 v[8];
        #pragma unroll
        for (int k = 0; k < 8; ++k)
            v[k] = rps[(size_t)(g + k) * D2_];
        #pragma unroll
        for (int k = 0; k < 8; k += 2) {
            #pragma unroll
            for (int j = 0; j < W_; ++j) {
                const bool b0 = (m[j] >> (g + k))     & 1u;  // uniform
                const bool b1 = (m[j] >> (g + k + 1)) & 1u;  // uniform
                float sx0 = b0 ? v[k].x     : ninf;   // v_cndmask
                float sy0 = b0 ? v[k].y     : ninf;
                float sx1 = b1 ? v[k + 1].x : ninf;
                float sy1 = b1 ? v[k + 1].y : ninf;
                // acc = max(acc, sel0, sel1) in ONE instruction.
                asm("v_max3_f32 %0, %1, %2, %3"
                    : "=v"(acc[j].x) : "v"(acc[j].x), "v"(sx0), "v"(sx1));
                asm("v_max3_f32 %0, %1, %2, %3"
                    : "=v"(acc[j].y) : "v"(acc[j].y), "v"(sy0), "v"(sy1));
            }
        }
    }

    // Merge the 8 segments via LDS.
    __shared__ float2 sacc[SEGS][W_][64];
    __shared__ unsigned int smask[SEGS][W_];
    #pragma unroll
    for (int j = 0; j < W_; ++j) sacc[s][j][lane] = acc[j];
    if (lane == 0) {
        #pragma unroll
        for (int j = 0; j < W_; ++j) smask[s][j] = m[j];
    }
    __syncthreads();

    // Wave j (< W_) finalizes word j.
    if (s < W_) {
        const int j = s;
        float2 r = sacc[0][j][lane];
        #pragma unroll
        for (int seg = 1; seg < SEGS; ++seg) {
            r.x = fmaxf(r.x, sacc[seg][j][lane].x);
            r.y = fmaxf(r.y, sacc[seg][j][lane].y);
        }
        unsigned int om = 0;
        #pragma unroll
        for (int seg = 0; seg < SEGS; ++seg) om |= smask[seg][j];

        if (om == 0u) {
            // Never taken for the fixed inputs; correct fallback = global
            // min over ALL of emb (reference min_value semantics).
            const float4* x = (const float4*)emb;
            const int n4 = (B_ * LP_ * D_) / 4;
            float mn = __uint_as_float(0x7F800000u);  // +inf
            for (int i = lane; i < n4; i += 64) {
                float4 vv = x[i];
                mn = fminf(mn, fminf(fminf(vv.x, vv.y), fminf(vv.z, vv.w)));
            }
            #pragma unroll
            for (int off = 32; off > 0; off >>= 1)
                mn = fminf(mn, __shfl_down(mn, off, 64));
            mn = __shfl(mn, 0, 64);
            r = make_float2(mn, mn);
        }

        float2* op = (float2*)out + (size_t)(b * LW_ + w0 + j) * D2_
                     + chunk * 64 + lane;
        *op = r;
    }
}

extern "C" void kernel_launch(void* const* d_in, const int* in_sizes, int n_in,
                              void* d_out, int out_size, void* d_ws, size_t ws_size,
                              hipStream_t stream) {
    const float* emb = (const float*)d_in[0];
    const int*   p2w = (const int*)d_in[1];
    float*       out = (float*)d_out;
    (void)d_ws; (void)ws_size;

    word_max_scan<<<NBLK, 512, 0, stream>>>(emb, p2w, out);
}

// Round 3
// 65.953 us; speedup vs baseline: 1.0202x; 1.0105x over previous
//
#include <hip/hip_runtime.h>

// Problem shape (fixed by reference setup_inputs):
//   bert_emb:    [B=4, Lp=256, D=768] fp32
//   pieces2word: [B=4, Lw=200, Lp=256] int32 (0/1)
//   out:         [B=4, Lw=200, D=768] fp32
// out[b,w,d] = max over {p : mask[b,w,p]!=0} of emb[b,p,d], else global min(emb).
//
// R13 — float4 data path (CHUNKS 6 -> 3), keeps R12's v_max3 pair-merge.
//  Why: R12 under-delivered vs its VALU prediction -> scalar-pipe co-bound.
//  Each gate (uniform mask bit -> VCC via s_bitcmp1+s_cselect_b64) is per
//  (piece-pair, word), INDEPENDENT of floats gated. The scalar unit is
//  per-CU (shared by 4 SIMDs): 30 waves/CU x ~320 SALU = ~4.0 us/CU,
//  exceeding the ~3.0 us per-SIMD VALU cost. float4 halves waves at same
//  SALU/wave -> SALU/CU ~2.0 us; VALU total unchanged; VMEM insts halve.
//  Grid: 480 blocks x 512 threads (8 waves, 15 waves/CU, ~3.75/SIMD).
//  Latency self-hidden: ~480 cy of merge VALU per unroll-8 load batch vs
//  ~200 cy L2 latency.
//
// Structure otherwise = R6/R12: block = (b, chunk of 256 floats, group of
// W=5 words); wave s owns pieces [32s,32s+32): ballots 5x32-bit masks,
// streams 32 emb row-chunks (dwordx4), merges branchlessly
// (cndmask + v_max3, 1.5 VALU/elem); LDS merge of 8 segments (41 KB).
// acc init = -inf bit-exact; empty-mask word -> global-min fallback.

#define B_  4
#define LP_ 256
#define LW_ 200
#define D_  768
#define D4_ (D_ / 4)              // 192 float4 per row
#define CHUNKS 3                  // 3 chunks x 256 floats (1 float4 per lane)
#define W_  5                     // words per block
#define WG_ (LW_ / W_)            // 40 word-groups
#define NBLK (B_ * CHUNKS * WG_)  // 480 blocks
#define SEGS 8                    // waves (piece segments) per block
#define PPS 32                    // pieces per segment

__global__ __launch_bounds__(512) void word_max_scan(
    const float* __restrict__ emb, const int* __restrict__ p2w,
    float* __restrict__ out)
{
    const int blk   = blockIdx.x;
    const int wg    = blk % WG_;
    const int rest  = blk / WG_;
    const int chunk = rest % CHUNKS;
    const int b     = rest / CHUNKS;
    const int lane  = threadIdx.x & 63;
    const int s     = threadIdx.x >> 6;     // piece segment 0..7
    const int w0    = wg * W_;

    // Each wave ballots a 32-bit mask for its 32 pieces, per word.
    unsigned int m[W_];
    const int pc = s * PPS + (lane & 31);
    #pragma unroll
    for (int j = 0; j < W_; ++j) {
        const int* mrow = p2w + (b * LW_ + w0 + j) * LP_;
        m[j] = (unsigned int)__ballot((lane < 32) && (mrow[pc] != 0));
    }

    const float ninf = __uint_as_float(0xFF800000u);
    float4 acc[W_];
    #pragma unroll
    for (int j = 0; j < W_; ++j) acc[j] = make_float4(ninf, ninf, ninf, ninf);

    // Wave's row stream: rows [32s, 32s+32), column = chunk*64 + lane (float4).
    const float4* rps = (const float4*)(emb + (size_t)b * LP_ * D_)
                        + chunk * 64 + lane + (size_t)(s * PPS) * D4_;

    #pragma unroll
    for (int g = 0; g < PPS; g += 8) {
        float4 v[8];
        #pragma unroll
        for (int k = 0; k < 8; ++k)
            v[k] = rps[(size_t)(g + k) * D4_];
        #pragma unroll
        for (int k = 0; k < 8; k += 2) {
            #pragma unroll
            for (int j = 0; j < W_; ++j) {
                const bool b0 = (m[j] >> (g + k))     & 1u;  // uniform
                const bool b1 = (m[j] >> (g + k + 1)) & 1u;  // uniform
                // One VCC per bit gates FOUR cndmasks (amortized SALU).
                float sx0 = b0 ? v[k].x     : ninf;
                float sy0 = b0 ? v[k].y     : ninf;
                float sz0 = b0 ? v[k].z     : ninf;
                float sw0 = b0 ? v[k].w     : ninf;
                float sx1 = b1 ? v[k + 1].x : ninf;
                float sy1 = b1 ? v[k + 1].y : ninf;
                float sz1 = b1 ? v[k + 1].z : ninf;
                float sw1 = b1 ? v[k + 1].w : ninf;
                asm("v_max3_f32 %0, %1, %2, %3"
                    : "=v"(acc[j].x) : "v"(acc[j].x), "v"(sx0), "v"(sx1));
                asm("v_max3_f32 %0, %1, %2, %3"
                    : "=v"(acc[j].y) : "v"(acc[j].y), "v"(sy0), "v"(sy1));
                asm("v_max3_f32 %0, %1, %2, %3"
                    : "=v"(acc[j].z) : "v"(acc[j].z), "v"(sz0), "v"(sz1));
                asm("v_max3_f32 %0, %1, %2, %3"
                    : "=v"(acc[j].w) : "v"(acc[j].w), "v"(sw0), "v"(sw1));
            }
        }
    }

    // Merge the 8 segments via LDS (8 x 5 x 64 x 16B = 40 KB + masks).
    __shared__ float4 sacc[SEGS][W_][64];
    __shared__ unsigned int smask[SEGS][W_];
    #pragma unroll
    for (int j = 0; j < W_; ++j) sacc[s][j][lane] = acc[j];
    if (lane == 0) {
        #pragma unroll
        for (int j = 0; j < W_; ++j) smask[s][j] = m[j];
    }
    __syncthreads();

    // Wave j (< W_) finalizes word j.
    if (s < W_) {
        const int j = s;
        float4 r = sacc[0][j][lane];
        #pragma unroll
        for (int seg = 1; seg < SEGS; ++seg) {
            r.x = fmaxf(r.x, sacc[seg][j][lane].x);
            r.y = fmaxf(r.y, sacc[seg][j][lane].y);
            r.z = fmaxf(r.z, sacc[seg][j][lane].z);
            r.w = fmaxf(r.w, sacc[seg][j][lane].w);
        }
        unsigned int om = 0;
        #pragma unroll
        for (int seg = 0; seg < SEGS; ++seg) om |= smask[seg][j];

        if (om == 0u) {
            // Never taken for the fixed inputs; correct fallback = global
            // min over ALL of emb (reference min_value semantics).
            const float4* x = (const float4*)emb;
            const int n4 = (B_ * LP_ * D_) / 4;
            float mn = __uint_as_float(0x7F800000u);  // +inf
            for (int i = lane; i < n4; i += 64) {
                float4 vv = x[i];
                mn = fminf(mn, fminf(fminf(vv.x, vv.y), fminf(vv.z, vv.w)));
            }
            #pragma unroll
            for (int off = 32; off > 0; off >>= 1)
                mn = fminf(mn, __shfl_down(mn, off, 64));
            mn = __shfl(mn, 0, 64);
            r = make_float4(mn, mn, mn, mn);
        }

        float4* op = (float4*)out + (size_t)(b * LW_ + w0 + j) * D4_
                     + chunk * 64 + lane;
        *op = r;
    }
}

extern "C" void kernel_launch(void* const* d_in, const int* in_sizes, int n_in,
                              void* d_out, int out_size, void* d_ws, size_t ws_size,
                              hipStream_t stream) {
    const float* emb = (const float*)d_in[0];
    const int*   p2w = (const int*)d_in[1];
    float*       out = (float*)d_out;
    (void)d_ws; (void)ws_size;

    word_max_scan<<<NBLK, 512, 0, stream>>>(emb, p2w, out);
}